// Round 5
// baseline (1420.773 us; speedup 1.0000x reference)
//
#include <hip/hip_runtime.h>
#include <stdint.h>

typedef _Float16 f16;
typedef _Float16 f16x8 __attribute__((ext_vector_type(8)));
typedef float f32x4 __attribute__((ext_vector_type(4)));

#define NCH   512
#define IMH   252
#define IMW   252
#define HWSZ  (IMH*IMW)          // 63504
#define NP    84
#define PN    (NP*NP)            // 7056
#define PPAD  7168               // 56*128
#define DD    (NCH*9)            // 4608
#define KK2   (PPAD*9)           // 64512 (gram K, padded)
#define KSPLIT 48
#define KCH   (KK2/KSPLIT)       // 1344 (42 K-steps of 32)
#define MARGIN 1.0f

#define AS1(p) ((const __attribute__((address_space(1))) void*)(p))
#define AS3(p) ((__attribute__((address_space(3))) void*)(p))

// ---------------- init: zero pad rows of packs + counters ----------------
__global__ void k_init(f16* __restrict__ I, f16* __restrict__ S,
                       int* cnt, float* msum) {
  unsigned t = blockIdx.x * blockDim.x + threadIdx.x;
  if (t == 0) { *cnt = 0; *msum = 0.0f; }
  const unsigned padN = (PPAD - PN) * DD;   // 516096
  for (unsigned i = t; i < padN; i += gridDim.x * blockDim.x) {
    I[(size_t)PN * DD + i] = (f16)0.0f;
    S[(size_t)PN * DD + i] = (f16)0.0f;
  }
}

// ---------------- mask sum ----------------
__global__ void k_masksum(const float* __restrict__ mask, float* msum) {
  __shared__ float red[256];
  float s = 0.f;
  for (unsigned i = blockIdx.x * 256 + threadIdx.x; i < HWSZ; i += gridDim.x * 256)
    s += mask[i];
  red[threadIdx.x] = s; __syncthreads();
  for (int st = 128; st > 0; st >>= 1) {
    if ((int)threadIdx.x < st) red[threadIdx.x] += red[threadIdx.x + st];
    __syncthreads();
  }
  if (threadIdx.x == 0) atomicAdd(msum, red[0]);
}

// ---------------- pack fm [C][H][W] fp32 -> patches [PPAD][DD] f16 ----------------
// f16x8 vector stores (DD % 8 == 0 so each chunk stays within one patch row).
__global__ void k_pack(const float* __restrict__ fm, f16* __restrict__ out) {
  const unsigned total8 = PN * DD / 8; // 4064256
  for (unsigned e8 = blockIdx.x * blockDim.x + threadIdx.x; e8 < total8;
       e8 += gridDim.x * blockDim.x) {
    const unsigned base = e8 * 8;
    const unsigned p = base / DD;
    const unsigned d0 = base - p * DD;
    const unsigned py = (p / NP) * 3, px = (p % NP) * 3;
    f16x8 v;
#pragma unroll
    for (int k = 0; k < 8; ++k) {
      unsigned d = d0 + k;
      unsigned c = d / 9, j = d - c * 9;
      v[k] = (f16)fm[(size_t)c * HWSZ + (py + j / 3) * IMW + px + j % 3];
    }
    *(f16x8*)(out + base) = v;
  }
}

// ---------------- score GEMM: SC[p][q] = I[p][:] . S[q][:], f16 out ----------------
// 128x128 tile, m97 structure: global_load_lds width=16, 2 barriers/K-step.
__global__ __launch_bounds__(256, 3)
void k_gemm(const f16* __restrict__ A, const f16* __restrict__ B,
            f16* __restrict__ out) {
  __shared__ f16 As[128][32];
  __shared__ f16 Bs[128][32];
  const int tid = threadIdx.x;
  const int w = tid >> 6, l = tid & 63;
  const int nwg = (PPAD / 128) * (PPAD / 128);   // 3136, divisible by 8
  int bid = blockIdx.x;
  bid = (bid & 7) * (nwg >> 3) + (bid >> 3);     // XCD-aware swizzle (bijective)
  const int bx = bid % (PPAD / 128), by = bid / (PPAD / 128);
  const size_t row0 = (size_t)by * 128, col0 = (size_t)bx * 128;
  const int wr = w >> 1, wc = w & 1;             // 2x2 wave grid, 64x64 each
  f32x4 acc[4][4] = {};
  const int sr = w * 32 + (l >> 2);              // staging row within 128-tile
  const int skb = (l & 3) * 8;                   // staging k element offset
  const f16* ga = A + (row0 + sr) * DD + skb;
  const f16* gb = B + (col0 + sr) * DD + skb;
  f16* lA0 = &As[w * 32][0];  f16* lA1 = &As[w * 32 + 16][0];
  f16* lB0 = &Bs[w * 32][0];  f16* lB1 = &Bs[w * 32 + 16][0];
  const int fr = l & 15, kb = (l >> 4) * 8;
  for (int k0 = 0; k0 < DD; k0 += 32) {
    __syncthreads();
    __builtin_amdgcn_global_load_lds(AS1(ga),           AS3(lA0), 16, 0, 0);
    __builtin_amdgcn_global_load_lds(AS1(ga + 16 * DD), AS3(lA1), 16, 0, 0);
    __builtin_amdgcn_global_load_lds(AS1(gb),           AS3(lB0), 16, 0, 0);
    __builtin_amdgcn_global_load_lds(AS1(gb + 16 * DD), AS3(lB1), 16, 0, 0);
    ga += 32; gb += 32;
    asm volatile("s_waitcnt vmcnt(0)" ::: "memory");
    __syncthreads();
    f16x8 af[4], bf[4];
#pragma unroll
    for (int i = 0; i < 4; ++i) af[i] = *(const f16x8*)&As[wr * 64 + i * 16 + fr][kb];
#pragma unroll
    for (int j = 0; j < 4; ++j) bf[j] = *(const f16x8*)&Bs[wc * 64 + j * 16 + fr][kb];
#pragma unroll
    for (int i = 0; i < 4; ++i)
#pragma unroll
      for (int j = 0; j < 4; ++j)
        acc[i][j] = __builtin_amdgcn_mfma_f32_16x16x32_f16(af[i], bf[j], acc[i][j], 0, 0, 0);
  }
  const int fq = l >> 4;
  const size_t orow = row0 + wr * 64, ocol = col0 + wc * 64;
#pragma unroll
  for (int i = 0; i < 4; ++i)
#pragma unroll
    for (int j = 0; j < 4; ++j)
#pragma unroll
      for (int r = 0; r < 4; ++r)
        out[(orow + i * 16 + fq * 4 + r) * PPAD + (ocol + j * 16 + fr)] =
            (f16)acc[i][j][r];
}

// ---------------- per-row top-2 + ambiguity detection (f16x8 loads) ----------------
__global__ void k_top2(const f16* __restrict__ sc, int* __restrict__ idx,
                       float* __restrict__ max1v, int* __restrict__ amb, int* cnt) {
  const int p = blockIdx.x;
  const f16x8* row8 = (const f16x8*)(sc + (size_t)p * PPAD);  // 16B-aligned
  float m1 = -1e30f, m2 = -1e30f; int i1 = 0;
  for (int v = threadIdx.x; v < PN / 8; v += 256) {           // 882 vectors
    f16x8 x = row8[v];
#pragma unroll
    for (int k = 0; k < 8; ++k) {
      float val = (float)x[k];
      if (val > m1) { m2 = m1; m1 = val; i1 = v * 8 + k; }
      else if (val > m2) m2 = val;
    }
  }
  __shared__ float sm1[256], sm2[256]; __shared__ int si1[256];
  const int t = threadIdx.x;
  sm1[t] = m1; sm2[t] = m2; si1[t] = i1; __syncthreads();
  for (int st = 128; st > 0; st >>= 1) {
    if (t < st) {
      float am1 = sm1[t], am2 = sm2[t]; int ai1 = si1[t];
      float bm1 = sm1[t + st], bm2 = sm2[t + st]; int bi1 = si1[t + st];
      if (bm1 > am1 || (bm1 == am1 && bi1 < ai1)) {
        sm1[t] = bm1; si1[t] = bi1; sm2[t] = fmaxf(am1, bm2);
      } else {
        sm2[t] = fmaxf(bm1, am2);
      }
    }
    __syncthreads();
  }
  if (t == 0) {
    idx[p] = si1[0]; max1v[p] = sm1[0];
    // ambiguous if f16 top-2 gap < MARGIN (covers f16-score error; exact
    // winner is then guaranteed to be in the rescore candidate set)
    if (sm2[0] > sm1[0] - MARGIN) { int a = atomicAdd(cnt, 1); amb[a] = p; }
  }
}

// ---------------- exact fp32 rescore of ambiguous rows (unbounded, ballot-scan) ----------------
__global__ void k_rescore(const float* __restrict__ img, const float* __restrict__ sty,
                          const f16* __restrict__ sc, const float* __restrict__ max1v,
                          const int* __restrict__ amb, const int* __restrict__ cnt,
                          int* __restrict__ idx) {
  __shared__ float red[256];
  __shared__ unsigned long long ball[4];
  const int t = threadIdx.x;
  const int n = *cnt;
  for (int r = blockIdx.x; r < n; r += gridDim.x) {
    const int p = amb[r];
    const float thr = max1v[p] - MARGIN;
    const f16* row = sc + (size_t)p * PPAD;
    const int py = (p / NP) * 3, px = (p % NP) * 3;
    float best = -1e30f; int bq = 0x7fffffff;
    for (int base = 0; base < PN; base += 256) {
      const int q = base + t;
      const bool is_cand = (q < PN) && ((float)row[q] >= thr);
      unsigned long long m = __ballot(is_cand);
      if ((t & 63) == 0) ball[t >> 6] = m;
      __syncthreads();
      // uniform scan of shared ballots: every thread walks the same bits
      for (int wv = 0; wv < 4; ++wv) {
        unsigned long long mm = ball[wv];
        while (mm) {
          const int b = __ffsll(mm) - 1; mm &= mm - 1;
          const int q2 = base + wv * 64 + b;
          const int qy = (q2 / NP) * 3, qx = (q2 % NP) * 3;
          float s = 0.f;
          for (int d = t; d < DD; d += 256) {
            int c = d / 9, j = d - c * 9, dy = j / 3, dx = j - dy * 3;
            s += img[(size_t)c * HWSZ + (py + dy) * IMW + (px + dx)] *
                 sty[(size_t)c * HWSZ + (qy + dy) * IMW + (qx + dx)];
          }
          red[t] = s; __syncthreads();
          for (int st = 128; st > 0; st >>= 1) {
            if (t < st) red[t] += red[t + st];
            __syncthreads();
          }
          const float tot = red[0];
          __syncthreads();   // everyone read red[0] before next dot reuses it
          if (tot > best || (tot == best && q2 < bq)) { best = tot; bq = q2; }
        }
      }
      __syncthreads();
    }
    if (t == 0) idx[p] = bq;
    __syncthreads();
  }
}

// ---------------- build masked f16 [NCH][KK2]: M[c][p*9+j] = S[idx[p]][c*9+j]*mask ----------------
__global__ void k_masked(const f16* __restrict__ S, const int* __restrict__ idx,
                         const float* __restrict__ mask, f16* __restrict__ M) {
  const int p = blockIdx.x;  // 0..PPAD-1
  if (p >= PN) {             // zero the K padding columns
    for (int e = threadIdx.x; e < NCH * 9; e += 256) {
      int c = e / 9, j = e - c * 9;
      M[(size_t)c * KK2 + p * 9 + j] = (f16)0.0f;
    }
    return;
  }
  __shared__ float mk[9];
  __shared__ int qs;
  if (threadIdx.x == 0) qs = idx[p];
  if (threadIdx.x < 9) {
    int j = threadIdx.x;
    mk[j] = mask[((p / NP) * 3 + j / 3) * IMW + (p % NP) * 3 + j % 3];
  }
  __syncthreads();
  const f16* srow = S + (size_t)qs * DD;
  for (int e = threadIdx.x; e < NCH * 9; e += 256) {
    int c = e / 9, j = e - c * 9;
    M[(size_t)c * KK2 + p * 9 + j] = (f16)((float)srow[e] * mk[j]);
  }
}

// ---------------- gram GEMM: part[chunk] = M_tile . M_tile^T (split-K=48) ----------------
__global__ __launch_bounds__(256, 3)
void k_gram(const f16* __restrict__ M, float* __restrict__ part) {
  __shared__ f16 As[128][32];
  __shared__ f16 Bs[128][32];
  const int tid = threadIdx.x;
  const int w = tid >> 6, l = tid & 63;
  const int tile = blockIdx.x & 15, chunk = blockIdx.x >> 4;
  const int bx = tile & 3, by = tile >> 2;
  const size_t row0 = (size_t)by * 128, col0 = (size_t)bx * 128;
  const int wr = w >> 1, wc = w & 1;
  f32x4 acc[4][4] = {};
  const int sr = w * 32 + (l >> 2);
  const int skb = (l & 3) * 8;
  const int kbeg = chunk * KCH;
  const f16* ga = M + (row0 + sr) * KK2 + kbeg + skb;
  const f16* gb = M + (col0 + sr) * KK2 + kbeg + skb;
  f16* lA0 = &As[w * 32][0];  f16* lA1 = &As[w * 32 + 16][0];
  f16* lB0 = &Bs[w * 32][0];  f16* lB1 = &Bs[w * 32 + 16][0];
  const int fr = l & 15, kb = (l >> 4) * 8;
  for (int k0 = 0; k0 < KCH; k0 += 32) {
    __syncthreads();
    __builtin_amdgcn_global_load_lds(AS1(ga),            AS3(lA0), 16, 0, 0);
    __builtin_amdgcn_global_load_lds(AS1(ga + 16 * KK2), AS3(lA1), 16, 0, 0);
    __builtin_amdgcn_global_load_lds(AS1(gb),            AS3(lB0), 16, 0, 0);
    __builtin_amdgcn_global_load_lds(AS1(gb + 16 * KK2), AS3(lB1), 16, 0, 0);
    ga += 32; gb += 32;
    asm volatile("s_waitcnt vmcnt(0)" ::: "memory");
    __syncthreads();
    f16x8 af[4], bf[4];
#pragma unroll
    for (int i = 0; i < 4; ++i) af[i] = *(const f16x8*)&As[wr * 64 + i * 16 + fr][kb];
#pragma unroll
    for (int j = 0; j < 4; ++j) bf[j] = *(const f16x8*)&Bs[wc * 64 + j * 16 + fr][kb];
#pragma unroll
    for (int i = 0; i < 4; ++i)
#pragma unroll
      for (int j = 0; j < 4; ++j)
        acc[i][j] = __builtin_amdgcn_mfma_f32_16x16x32_f16(af[i], bf[j], acc[i][j], 0, 0, 0);
  }
  const int fq = l >> 4;
  const size_t orow = row0 + wr * 64, ocol = col0 + wc * 64;
  float* pout = part + (size_t)chunk * (NCH * NCH);
#pragma unroll
  for (int i = 0; i < 4; ++i)
#pragma unroll
    for (int j = 0; j < 4; ++j)
#pragma unroll
      for (int r = 0; r < 4; ++r)
        pout[(orow + i * 16 + fq * 4 + r) * NCH + (ocol + j * 16 + fr)] = acc[i][j][r];
}

// ---------------- reduce partials + scale ----------------
__global__ void k_out(const float* __restrict__ part, const float* __restrict__ msum,
                      float* __restrict__ out) {
  const unsigned e = blockIdx.x * 256 + threadIdx.x;  // 0..262143
  float s = 0.f;
#pragma unroll
  for (int k = 0; k < KSPLIT; ++k) s += part[(size_t)k * (NCH * NCH) + e];
  out[e] = s / (*msum * (float)NCH);
}

extern "C" void kernel_launch(void* const* d_in, const int* in_sizes, int n_in,
                              void* d_out, int out_size, void* d_ws, size_t ws_size,
                              hipStream_t stream) {
  const float* style = (const float*)d_in[0];
  const float* img   = (const float*)d_in[1];
  const float* mask  = (const float*)d_in[2];
  float* out = (float*)d_out;
  char* ws = (char*)d_ws;

  const size_t SZP = (size_t)PPAD * DD * sizeof(f16);          // 66,060,288
  const size_t SZS = (size_t)PPAD * PPAD * sizeof(f16);        // 102,760,448
  f16* I  = (f16*)(ws);                       // img patches   (later: gram partials)
  f16* S  = (f16*)(ws + SZP);                 // style patches
  f16* SC = (f16*)(ws + 2 * SZP);             // scores        (later: masked matrix, 66MB)
  char* misc = ws + 2 * SZP + SZS;            // ~235 MiB total
  int*   idx   = (int*)(misc);
  float* max1v = (float*)(misc + 32768);
  int*   amb   = (int*)(misc + 65536);
  int*   cnt   = (int*)(misc + 98304);
  float* msum  = (float*)(misc + 98432);
  float* part  = (float*)(ws);                // reuses I region (50.3 MB < SZP)

  k_init   <<<256, 256, 0, stream>>>(I, S, cnt, msum);
  k_masksum<<<128, 256, 0, stream>>>(mask, msum);
  k_pack   <<<2048, 256, 0, stream>>>(img, I);
  k_pack   <<<2048, 256, 0, stream>>>(style, S);
  k_gemm   <<<(PPAD / 128) * (PPAD / 128), 256, 0, stream>>>(I, S, SC);
  k_top2   <<<PN, 256, 0, stream>>>(SC, idx, max1v, amb, cnt);
  k_rescore<<<512, 256, 0, stream>>>(img, style, SC, max1v, amb, cnt, idx);
  k_masked <<<PPAD, 256, 0, stream>>>(S, idx, mask, SC);
  k_gram   <<<16 * KSPLIT, 256, 0, stream>>>((const f16*)SC, part);
  k_out    <<<(NCH * NCH) / 256, 256, 0, stream>>>(part, msum, out);
}

// Round 9
// 1316.228 us; speedup vs baseline: 1.0794x; 1.0794x over previous
//
#include <hip/hip_runtime.h>
#include <stdint.h>

typedef _Float16 f16;
typedef _Float16 f16x8 __attribute__((ext_vector_type(8)));
typedef float f32x4 __attribute__((ext_vector_type(4)));

#define NCH   512
#define IMH   252
#define IMW   252
#define HWSZ  (IMH*IMW)          // 63504
#define NP    84
#define PN    (NP*NP)            // 7056
#define PPAD  7168               // 28*256
#define DD    (NCH*9)            // 4608
#define KK2   (PPAD*9)           // 64512 (gram K, padded)
#define KSPLIT 48
#define KCH   (KK2/KSPLIT)       // 1344 (42 K-steps of 32)
#define MARGIN 1.0f

#define AS1(p) ((const __attribute__((address_space(1))) void*)(p))
#define AS3(p) ((__attribute__((address_space(3))) void*)(p))

// ---------------- init: zero pad rows of packs + counters ----------------
__global__ void k_init(f16* __restrict__ I, f16* __restrict__ S,
                       int* cnt, float* msum) {
  unsigned t = blockIdx.x * blockDim.x + threadIdx.x;
  if (t == 0) { *cnt = 0; *msum = 0.0f; }
  const unsigned padN = (PPAD - PN) * DD;   // 516096
  for (unsigned i = t; i < padN; i += gridDim.x * blockDim.x) {
    I[(size_t)PN * DD + i] = (f16)0.0f;
    S[(size_t)PN * DD + i] = (f16)0.0f;
  }
}

// ---------------- mask sum ----------------
__global__ void k_masksum(const float* __restrict__ mask, float* msum) {
  __shared__ float red[256];
  float s = 0.f;
  for (unsigned i = blockIdx.x * 256 + threadIdx.x; i < HWSZ; i += gridDim.x * 256)
    s += mask[i];
  red[threadIdx.x] = s; __syncthreads();
  for (int st = 128; st > 0; st >>= 1) {
    if ((int)threadIdx.x < st) red[threadIdx.x] += red[threadIdx.x + st];
    __syncthreads();
  }
  if (threadIdx.x == 0) atomicAdd(msum, red[0]);
}

// ---------------- pack fm [C][H][W] fp32 -> patches [PPAD][DD] f16 ----------------
// LDS-transposed: block (py, cg32). Coalesced reads, 576B-contiguous writes.
__global__ __launch_bounds__(256)
void k_pack(const float* __restrict__ fm, f16* __restrict__ out) {
  __shared__ f16 T[32 * 756];                 // [cc][r*252+x]
  const int py = blockIdx.x >> 4, cg = blockIdx.x & 15;
  const int c0 = cg * 32;
  for (int e = threadIdx.x; e < 32 * 756; e += 256) {
    int cc = e / 756, rx = e - cc * 756;      // rx = r*252+x, r<3
    T[e] = (f16)fm[(size_t)(c0 + cc) * HWSZ +
                   (size_t)(py * 3 + rx / 252) * IMW + (rx % 252)];
  }
  __syncthreads();
  for (int v = threadIdx.x; v < 84 * 36; v += 256) {
    int pxi = v / 36, d0 = (v - pxi * 36) * 8;  // d0 in [0,288)
    f16x8 o;
#pragma unroll
    for (int k = 0; k < 8; ++k) {
      int d = d0 + k, cc = d / 9, j = d - cc * 9;
      o[k] = T[cc * 756 + (j / 3) * 252 + pxi * 3 + (j % 3)];
    }
    *(f16x8*)(out + (size_t)(py * NP + pxi) * DD + c0 * 9 + d0) = o;
  }
}

// ---------------- score GEMM 256x256, BK=32, 4-buf counted-vmcnt pipeline ----
// T3/T4 essence: stage tile t+3 each iter, vmcnt(12) = 3 tiles (12 loads/wave)
// in flight, never drained to 0; raw s_barrier (NOT __syncthreads -> no
// vmcnt(0) drain). RACE INVARIANT (verified pair-by-pair): STG at iter t
// writes buf (t+3)&3 == (t-1)&3, whose last readers ran at iter t-1; those
// ds_reads retire via lgkmcnt(0)+sched_barrier(0) BEFORE the end-of-(t-1)
// s_barrier, and no wave issues iter-t STGs until all waves passed that
// barrier. Cross-wave data: per-wave vmcnt(12) covers own tile-t loads; the
// start-of-iter barrier then guarantees ALL waves' tile-t loads landed.
// Clamped-tail STGs (t>=NT-3) rewrite tile NT-1 into bufs never read again.
// Fragment formulas identical to the bench-validated 128^2 kernel.
__global__ __launch_bounds__(512, 2)
void k_gemm256(const f16* __restrict__ A, const f16* __restrict__ B,
               f16* __restrict__ out) {
  __shared__ f16 Al[4][256][32];   // 64 KiB
  __shared__ f16 Bl[4][256][32];   // 64 KiB
  const int tid = threadIdx.x, w = tid >> 6, l = tid & 63;
  int bid = blockIdx.x;
  bid = (bid & 7) * 98 + (bid >> 3);           // 784 = 8*98, bijective
  const int bx = bid % 28, by = bid / 28;
  const size_t row0 = (size_t)by * 256, col0 = (size_t)bx * 256;
  const int wm = w >> 2, wn = w & 3;           // 2x4 wave grid, 128x64 each
  f32x4 acc[8][4] = {};
  // staging: per tile, 4 gload_lds/wave; lane l covers LDS byte base+l*16
  const int srow = w * 16 + (l >> 2);          // 0..127
  const int scol = (l & 3) * 8;                // element offset
  const f16* gA0 = A + (row0 + srow) * DD + scol;
  const f16* gA1 = A + (row0 + srow + 128) * DD + scol;
  const f16* gB0 = B + (col0 + srow) * DD + scol;
  const f16* gB1 = B + (col0 + srow + 128) * DD + scol;
  const int ldst = w * 512 + l * 8;            // f16 units in [256][32] buf
#define STG(tt, bb) do {                                                        \
    __builtin_amdgcn_global_load_lds(AS1(gA0 + (tt)*32), AS3(&Al[bb][0][0] + ldst),        16, 0, 0); \
    __builtin_amdgcn_global_load_lds(AS1(gA1 + (tt)*32), AS3(&Al[bb][0][0] + 4096 + ldst), 16, 0, 0); \
    __builtin_amdgcn_global_load_lds(AS1(gB0 + (tt)*32), AS3(&Bl[bb][0][0] + ldst),        16, 0, 0); \
    __builtin_amdgcn_global_load_lds(AS1(gB1 + (tt)*32), AS3(&Bl[bb][0][0] + 4096 + ldst), 16, 0, 0); \
  } while (0)
  STG(0, 0); STG(1, 1); STG(2, 2);             // prologue: 3 tiles in flight
  const int fr = l & 15, kb = (l >> 4) * 8;
  const int NT = DD / 32;                      // 144
  for (int t = 0; t < NT; ++t) {
    const int ts = (t + 3 < NT) ? t + 3 : NT - 1;  // clamped: keeps vmcnt uniform
    const int bb = t & 3;
    STG(ts, (t + 3) & 3);                      // writes buf read at t-1; safe:
                                               // issued after end-of-(t-1) barrier
    asm volatile("s_waitcnt vmcnt(12)" ::: "memory");  // own tile-t loads landed
    __builtin_amdgcn_s_barrier();              // => all waves' tile-t loads landed
    __builtin_amdgcn_sched_barrier(0);         // no ds_read hoists above barrier
    f16x8 af[8], bf[4];
#pragma unroll
    for (int i = 0; i < 8; ++i) af[i] = *(const f16x8*)&Al[bb][wm * 128 + i * 16 + fr][kb];
#pragma unroll
    for (int j = 0; j < 4; ++j) bf[j] = *(const f16x8*)&Bl[bb][wn * 64 + j * 16 + fr][kb];
#pragma unroll
    for (int i = 0; i < 8; ++i)
#pragma unroll
      for (int j = 0; j < 4; ++j)
        acc[i][j] = __builtin_amdgcn_mfma_f32_16x16x32_f16(af[i], bf[j], acc[i][j], 0, 0, 0);
    asm volatile("s_waitcnt lgkmcnt(0)" ::: "memory");  // ds_reads retired...
    __builtin_amdgcn_sched_barrier(0);                  // ...pinned before barrier
    __builtin_amdgcn_s_barrier();              // end-of-t: licenses t+1's STG
  }
#undef STG
  const int fq = l >> 4;
  const size_t orow = row0 + wm * 128, ocol = col0 + wn * 64;
#pragma unroll
  for (int i = 0; i < 8; ++i)
#pragma unroll
    for (int j = 0; j < 4; ++j)
#pragma unroll
      for (int r = 0; r < 4; ++r)
        out[(orow + i * 16 + fq * 4 + r) * PPAD + (ocol + j * 16 + fr)] =
            (f16)acc[i][j][r];
}

// ---------------- per-row top-2 + ambiguity detection (f16x8 loads) ----------------
__global__ void k_top2(const f16* __restrict__ sc, int* __restrict__ idx,
                       float* __restrict__ max1v, int* __restrict__ amb, int* cnt) {
  const int p = blockIdx.x;
  const f16x8* row8 = (const f16x8*)(sc + (size_t)p * PPAD);  // 16B-aligned
  float m1 = -1e30f, m2 = -1e30f; int i1 = 0;
  for (int v = threadIdx.x; v < PN / 8; v += 256) {           // 882 vectors
    f16x8 x = row8[v];
#pragma unroll
    for (int k = 0; k < 8; ++k) {
      float val = (float)x[k];
      if (val > m1) { m2 = m1; m1 = val; i1 = v * 8 + k; }
      else if (val > m2) m2 = val;
    }
  }
  __shared__ float sm1[256], sm2[256]; __shared__ int si1[256];
  const int t = threadIdx.x;
  sm1[t] = m1; sm2[t] = m2; si1[t] = i1; __syncthreads();
  for (int st = 128; st > 0; st >>= 1) {
    if (t < st) {
      float am1 = sm1[t], am2 = sm2[t]; int ai1 = si1[t];
      float bm1 = sm1[t + st], bm2 = sm2[t + st]; int bi1 = si1[t + st];
      if (bm1 > am1 || (bm1 == am1 && bi1 < ai1)) {
        sm1[t] = bm1; si1[t] = bi1; sm2[t] = fmaxf(am1, bm2);
      } else {
        sm2[t] = fmaxf(bm1, am2);
      }
    }
    __syncthreads();
  }
  if (t == 0) {
    idx[p] = si1[0]; max1v[p] = sm1[0];
    if (sm2[0] > sm1[0] - MARGIN) { int a = atomicAdd(cnt, 1); amb[a] = p; }
  }
}

// ---------------- exact fp32 rescore of ambiguous rows (unbounded, ballot-scan) ----------------
__global__ void k_rescore(const float* __restrict__ img, const float* __restrict__ sty,
                          const f16* __restrict__ sc, const float* __restrict__ max1v,
                          const int* __restrict__ amb, const int* __restrict__ cnt,
                          int* __restrict__ idx) {
  __shared__ float red[256];
  __shared__ unsigned long long ball[4];
  const int t = threadIdx.x;
  const int n = *cnt;
  for (int r = blockIdx.x; r < n; r += gridDim.x) {
    const int p = amb[r];
    const float thr = max1v[p] - MARGIN;
    const f16* row = sc + (size_t)p * PPAD;
    const int py = (p / NP) * 3, px = (p % NP) * 3;
    float best = -1e30f; int bq = 0x7fffffff;
    for (int base = 0; base < PN; base += 256) {
      const int q = base + t;
      const bool is_cand = (q < PN) && ((float)row[q] >= thr);
      unsigned long long m = __ballot(is_cand);
      if ((t & 63) == 0) ball[t >> 6] = m;
      __syncthreads();
      for (int wv = 0; wv < 4; ++wv) {
        unsigned long long mm = ball[wv];
        while (mm) {
          const int b = __ffsll(mm) - 1; mm &= mm - 1;
          const int q2 = base + wv * 64 + b;
          const int qy = (q2 / NP) * 3, qx = (q2 % NP) * 3;
          float s = 0.f;
          for (int d = t; d < DD; d += 256) {
            int c = d / 9, j = d - c * 9, dy = j / 3, dx = j - dy * 3;
            s += img[(size_t)c * HWSZ + (py + dy) * IMW + (px + dx)] *
                 sty[(size_t)c * HWSZ + (qy + dy) * IMW + (qx + dx)];
          }
          red[t] = s; __syncthreads();
          for (int st = 128; st > 0; st >>= 1) {
            if (t < st) red[t] += red[t + st];
            __syncthreads();
          }
          const float tot = red[0];
          __syncthreads();
          if (tot > best || (tot == best && q2 < bq)) { best = tot; bq = q2; }
        }
      }
      __syncthreads();
    }
    if (t == 0) idx[p] = bq;
    __syncthreads();
  }
}

// ---------------- build masked f16 [NCH][KK2] (LDS-transposed, coalesced) ----------------
__global__ __launch_bounds__(256)
void k_masked(const f16* __restrict__ S, const int* __restrict__ idx,
              const float* __restrict__ mask, f16* __restrict__ M) {
  __shared__ f16 B[84 * 288];                 // [pxi][cc*9+j]
  __shared__ float mrow[756];                 // 3 mask rows
  __shared__ int qv[84];
  const int py = blockIdx.x >> 4, cg = blockIdx.x & 15;
  const int c0 = cg * 32;
  for (int e = threadIdx.x; e < 756; e += 256)
    mrow[e] = mask[(size_t)(py * 3 + e / 252) * IMW + (e % 252)];
  if (threadIdx.x < 84) qv[threadIdx.x] = idx[py * NP + threadIdx.x];
  __syncthreads();
  for (int v = threadIdx.x; v < 84 * 36; v += 256) {
    int pxi = v / 36, d0 = (v - pxi * 36) * 8;
    f16x8 x = *(const f16x8*)(S + (size_t)qv[pxi] * DD + c0 * 9 + d0);
    f16x8 o;
#pragma unroll
    for (int k = 0; k < 8; ++k) {
      int j = (d0 + k) % 9;
      o[k] = (f16)((float)x[k] * mrow[(j / 3) * 252 + pxi * 3 + (j % 3)]);
    }
    *(f16x8*)(&B[pxi * 288 + d0]) = o;
  }
  __syncthreads();
  for (int e = threadIdx.x; e < 32 * 756; e += 256) {
    int cc = e / 756, r = e - cc * 756;       // r = pxi*9+j
    M[(size_t)(c0 + cc) * KK2 + (size_t)py * 756 + r] =
        B[(r / 9) * 288 + cc * 9 + (r % 9)];
  }
}

// ---------------- zero gram-K padding columns (p in [PN,PPAD)) ----------------
__global__ void k_mpad(f16* __restrict__ M) {
  const unsigned per_c = (PPAD - PN) * 9;     // 1008
  const unsigned total = NCH * per_c;         // 516096
  for (unsigned e = blockIdx.x * 256 + threadIdx.x; e < total;
       e += gridDim.x * 256) {
    unsigned c = e / per_c, r = e - c * per_c;
    M[(size_t)c * KK2 + (size_t)PN * 9 + r] = (f16)0.0f;
  }
}

// ---------------- gram GEMM: part[chunk] = M_tile . M_tile^T (split-K=48) ----------------
__global__ __launch_bounds__(256, 3)
void k_gram(const f16* __restrict__ M, float* __restrict__ part) {
  __shared__ f16 As[128][32];
  __shared__ f16 Bs[128][32];
  const int tid = threadIdx.x;
  const int w = tid >> 6, l = tid & 63;
  const int tile = blockIdx.x & 15, chunk = blockIdx.x >> 4;
  const int bx = tile & 3, by = tile >> 2;
  const size_t row0 = (size_t)by * 128, col0 = (size_t)bx * 128;
  const int wr = w >> 1, wc = w & 1;
  f32x4 acc[4][4] = {};
  const int sr = w * 32 + (l >> 2);
  const int skb = (l & 3) * 8;
  const int kbeg = chunk * KCH;
  const f16* ga = M + (row0 + sr) * KK2 + kbeg + skb;
  const f16* gb = M + (col0 + sr) * KK2 + kbeg + skb;
  f16* lA0 = &As[w * 32][0];  f16* lA1 = &As[w * 32 + 16][0];
  f16* lB0 = &Bs[w * 32][0];  f16* lB1 = &Bs[w * 32 + 16][0];
  const int fr = l & 15, kb = (l >> 4) * 8;
  for (int k0 = 0; k0 < KCH; k0 += 32) {
    __syncthreads();
    __builtin_amdgcn_global_load_lds(AS1(ga),            AS3(lA0), 16, 0, 0);
    __builtin_amdgcn_global_load_lds(AS1(ga + 16 * KK2), AS3(lA1), 16, 0, 0);
    __builtin_amdgcn_global_load_lds(AS1(gb),            AS3(lB0), 16, 0, 0);
    __builtin_amdgcn_global_load_lds(AS1(gb + 16 * KK2), AS3(lB1), 16, 0, 0);
    ga += 32; gb += 32;
    asm volatile("s_waitcnt vmcnt(0)" ::: "memory");
    __syncthreads();
    f16x8 af[4], bf[4];
#pragma unroll
    for (int i = 0; i < 4; ++i) af[i] = *(const f16x8*)&As[wr * 64 + i * 16 + fr][kb];
#pragma unroll
    for (int j = 0; j < 4; ++j) bf[j] = *(const f16x8*)&Bs[wc * 64 + j * 16 + fr][kb];
#pragma unroll
    for (int i = 0; i < 4; ++i)
#pragma unroll
      for (int j = 0; j < 4; ++j)
        acc[i][j] = __builtin_amdgcn_mfma_f32_16x16x32_f16(af[i], bf[j], acc[i][j], 0, 0, 0);
  }
  const int fq = l >> 4;
  const size_t orow = row0 + wr * 64, ocol = col0 + wc * 64;
  float* pout = part + (size_t)chunk * (NCH * NCH);
#pragma unroll
  for (int i = 0; i < 4; ++i)
#pragma unroll
    for (int j = 0; j < 4; ++j)
#pragma unroll
      for (int r = 0; r < 4; ++r)
        pout[(orow + i * 16 + fq * 4 + r) * NCH + (ocol + j * 16 + fr)] = acc[i][j][r];
}

// ---------------- reduce partials + scale ----------------
__global__ void k_out(const float* __restrict__ part, const float* __restrict__ msum,
                      float* __restrict__ out) {
  const unsigned e = blockIdx.x * 256 + threadIdx.x;  // 0..262143
  float s = 0.f;
#pragma unroll
  for (int k = 0; k < KSPLIT; ++k) s += part[(size_t)k * (NCH * NCH) + e];
  out[e] = s / (*msum * (float)NCH);
}

extern "C" void kernel_launch(void* const* d_in, const int* in_sizes, int n_in,
                              void* d_out, int out_size, void* d_ws, size_t ws_size,
                              hipStream_t stream) {
  const float* style = (const float*)d_in[0];
  const float* img   = (const float*)d_in[1];
  const float* mask  = (const float*)d_in[2];
  float* out = (float*)d_out;
  char* ws = (char*)d_ws;

  const size_t SZP = (size_t)PPAD * DD * sizeof(f16);          // 66,060,288
  const size_t SZS = (size_t)PPAD * PPAD * sizeof(f16);        // 102,760,448
  f16* I  = (f16*)(ws);                       // img patches   (later: gram partials)
  f16* S  = (f16*)(ws + SZP);                 // style patches
  f16* SC = (f16*)(ws + 2 * SZP);             // scores        (later: masked matrix, 66MB)
  char* misc = ws + 2 * SZP + SZS;            // ~235 MiB total
  int*   idx   = (int*)(misc);
  float* max1v = (float*)(misc + 32768);
  int*   amb   = (int*)(misc + 65536);
  int*   cnt   = (int*)(misc + 98304);
  float* msum  = (float*)(misc + 98432);
  float* part  = (float*)(ws);                // reuses I region (50.3 MB < SZP)

  k_init   <<<256, 256, 0, stream>>>(I, S, cnt, msum);
  k_masksum<<<128, 256, 0, stream>>>(mask, msum);
  k_pack   <<<84 * 16, 256, 0, stream>>>(img, I);
  k_pack   <<<84 * 16, 256, 0, stream>>>(style, S);
  k_gemm256<<<(PPAD / 256) * (PPAD / 256), 512, 0, stream>>>(I, S, SC);
  k_top2   <<<PN, 256, 0, stream>>>(SC, idx, max1v, amb, cnt);
  k_rescore<<<512, 256, 0, stream>>>(img, style, SC, max1v, amb, cnt, idx);
  k_masked <<<84 * 16, 256, 0, stream>>>(S, idx, mask, SC);
  k_mpad   <<<128, 256, 0, stream>>>(SC);
  k_gram   <<<16 * KSPLIT, 256, 0, stream>>>((const f16*)SC, part);
  k_out    <<<(NCH * NCH) / 256, 256, 0, stream>>>(part, msum, out);
}